// Round 8
// baseline (139.017 us; speedup 1.0000x reference)
//
#include <hip/hip_runtime.h>

#define Bv 4
#define Vv 50000
#define Cv 160

// Kernel 1: per-(b,c) affine table A[b][c][12]:
//   A[0..8]  = R row-major (rows b1,b2,b3)
//   A[9..11] = center + V_nodes - R*center
// so out[b,v,:] = M·x_v + t with [M|t] = sum_c W[v,c]*A[b,c,:]
__global__ void precompute_A(const float* __restrict__ X,
                             const float* __restrict__ Vn,
                             const float* __restrict__ r6,
                             const int* __restrict__ idx,
                             float* __restrict__ A) {
    int i = blockIdx.x * blockDim.x + threadIdx.x;
    if (i >= Bv * Cv) return;
    int b = i / Cv, c = i % Cv;

    const float* d6 = r6 + (size_t)(b * Cv + c) * 6;
    float a1x = d6[0], a1y = d6[1], a1z = d6[2];
    float a2x = d6[3], a2y = d6[4], a2z = d6[5];

    float n1 = fmaxf(sqrtf(a1x*a1x + a1y*a1y + a1z*a1z), 1e-8f);
    float b1x = a1x / n1, b1y = a1y / n1, b1z = a1z / n1;

    float d = b1x*a2x + b1y*a2y + b1z*a2z;
    float px = a2x - d*b1x, py = a2y - d*b1y, pz = a2z - d*b1z;
    float n2 = fmaxf(sqrtf(px*px + py*py + pz*pz), 1e-8f);
    float b2x = px / n2, b2y = py / n2, b2z = pz / n2;

    float b3x = b1y*b2z - b1z*b2y;
    float b3y = b1z*b2x - b1x*b2z;
    float b3z = b1x*b2y - b1y*b2x;

    int iv = idx[c];
    const float* xc = X + ((size_t)b * Vv + iv) * 3;
    float cx = xc[0], cy = xc[1], cz = xc[2];
    const float* vn = Vn + (size_t)(b * Cv + c) * 3;
    float vx = vn[0], vy = vn[1], vz = vn[2];

    float* Ao = A + (size_t)(b * Cv + c) * 12;
    Ao[0] = b1x; Ao[1] = b1y; Ao[2] = b1z;
    Ao[3] = b2x; Ao[4] = b2y; Ao[5] = b2z;
    Ao[6] = b3x; Ao[7] = b3y; Ao[8] = b3z;
    Ao[9]  = cx + vx - (b1x*cx + b1y*cy + b1z*cz);
    Ao[10] = cy + vy - (b2x*cx + b2y*cy + b2z*cz);
    Ao[11] = cz + vz - (b3x*cx + b3y*cy + b3z*cz);
}

// Kernel 2: 782 blocks x 256 thr = 4 waves (wave w -> batch b=w), 64
// vertices/block, 1 vertex/lane (R4's parallelism — the measured best).
// KEY CHANGE vs R4: W goes global->LDS with COALESCED float4 loads (8
// lines/instr), then ds_read_b128 in the hot loop. R4's per-lane-row W
// global loads cost 64 L1 line-lookups per instruction (~8M total) — the
// common ~30 us bottleneck of R4/R6/R7. A stays on the vector/vmcnt path
// (L1-broadcast, same address across the wave). ds_read (lgkmcnt) and
// global A (vmcnt) are independent counters; NO s_loads in the loop.
#define WSTR 164  // floats/row: 656 B = 41*16 -> b128-aligned; 8-phase bank pattern = b128 BW floor, no extra conflict
__global__ __launch_bounds__(256) void deform_main(const float* __restrict__ X,
                                                   const float* __restrict__ W,
                                                   const float* __restrict__ A,
                                                   float* __restrict__ out) {
    __shared__ float Wl[64 * WSTR];  // 42.0 KB -> 3 blocks/CU

    const int tid = threadIdx.x;
    const int v0  = blockIdx.x * 64;

    // Coalesced staging: 64 rows x 40 float4. Consecutive tids read
    // consecutive float4s of a row.
    for (int i4 = tid; i4 < 64 * 40; i4 += 256) {
        int r  = i4 / 40;
        int c4 = i4 % 40;
        int row = v0 + r;
        if (row >= Vv) row = Vv - 1;
        float4 q = ((const float4*)(W + (size_t)row * Cv))[c4];
        *(float4*)&Wl[r * WSTR + c4 * 4] = q;
    }
    __syncthreads();

    const int lane = tid & 63;
    const int b    = tid >> 6;            // uniform in fact; stays on vector path
    const int v    = v0 + lane;
    const bool valid = (v < Vv);
    const int vc   = valid ? v : (Vv - 1);

    const float4* __restrict__ wrow = (const float4*)&Wl[lane * WSTR];
    const float4* __restrict__ A4   = (const float4*)(A + (size_t)b * Cv * 12);

    const float* xp = X + ((size_t)b * Vv + vc) * 3;
    float x0 = xp[0], x1 = xp[1], x2 = xp[2];

    float acc[12];
#pragma unroll
    for (int j = 0; j < 12; ++j) acc[j] = 0.0f;

#pragma unroll 2
    for (int c4 = 0; c4 < Cv / 4; ++c4) {
        float4 wq = wrow[c4];             // ds_read_b128
        const float wj[4] = {wq.x, wq.y, wq.z, wq.w};
#pragma unroll
        for (int j = 0; j < 4; ++j) {
            int c = c4 * 4 + j;
            float4 a0 = A4[c * 3 + 0];    // M00 M01 M02 M10   (global, L1 broadcast)
            float4 a1 = A4[c * 3 + 1];    // M11 M12 M20 M21
            float4 a2 = A4[c * 3 + 2];    // M22 T0  T1  T2
            float w = wj[j];
            acc[0]  = fmaf(w, a0.x, acc[0]);
            acc[1]  = fmaf(w, a0.y, acc[1]);
            acc[2]  = fmaf(w, a0.z, acc[2]);
            acc[3]  = fmaf(w, a0.w, acc[3]);
            acc[4]  = fmaf(w, a1.x, acc[4]);
            acc[5]  = fmaf(w, a1.y, acc[5]);
            acc[6]  = fmaf(w, a1.z, acc[6]);
            acc[7]  = fmaf(w, a1.w, acc[7]);
            acc[8]  = fmaf(w, a2.x, acc[8]);
            acc[9]  = fmaf(w, a2.y, acc[9]);
            acc[10] = fmaf(w, a2.z, acc[10]);
            acc[11] = fmaf(w, a2.w, acc[11]);
        }
    }

    if (valid) {
        // acc groups: a0=(M00,M01,M02,M10) a1=(M11,M12,M20,M21) a2=(M22,T0,T1,T2)
        float o0 = acc[0]*x0 + acc[1]*x1 + acc[2]*x2  + acc[9];
        float o1 = acc[3]*x0 + acc[4]*x1 + acc[5]*x2  + acc[10];
        float o2 = acc[6]*x0 + acc[7]*x1 + acc[8]*x2  + acc[11];
        float* op = out + ((size_t)b * Vv + v) * 3;
        op[0] = o0; op[1] = o1; op[2] = o2;
    }
}

extern "C" void kernel_launch(void* const* d_in, const int* in_sizes, int n_in,
                              void* d_out, int out_size, void* d_ws, size_t ws_size,
                              hipStream_t stream) {
    const float* X   = (const float*)d_in[0];  // (B,V,3) fp32
    const float* Vn  = (const float*)d_in[1];  // (B,C,3) fp32
    const float* r6  = (const float*)d_in[2];  // (B,C,6) fp32
    const float* W   = (const float*)d_in[3];  // (V,C)   fp32
    const int*   idx = (const int*)d_in[4];    // (C,)    int32
    float* out = (float*)d_out;                // (B,V,3) fp32
    float* A = (float*)d_ws;                   // B*C*12 floats = 30720 B

    precompute_A<<<(Bv * Cv + 255) / 256, 256, 0, stream>>>(X, Vn, r6, idx, A);
    deform_main<<<(Vv + 63) / 64, 256, 0, stream>>>(X, W, A, out);
}

// Round 9
// 120.621 us; speedup vs baseline: 1.1525x; 1.1525x over previous
//
#include <hip/hip_runtime.h>

#define Bv 4
#define Vv 50000
#define Cv 160

// Kernel 1: per-(b,c) affine table A[b][c][12]:
//   A[0..8]  = R row-major (rows b1,b2,b3)
//   A[9..11] = center + V_nodes - R*center
// so out[b,v,:] = M·x_v + t with [M|t] = sum_c W[v,c]*A[b,c,:]
__global__ void precompute_A(const float* __restrict__ X,
                             const float* __restrict__ Vn,
                             const float* __restrict__ r6,
                             const int* __restrict__ idx,
                             float* __restrict__ A) {
    int i = blockIdx.x * blockDim.x + threadIdx.x;
    if (i >= Bv * Cv) return;
    int b = i / Cv, c = i % Cv;

    const float* d6 = r6 + (size_t)(b * Cv + c) * 6;
    float a1x = d6[0], a1y = d6[1], a1z = d6[2];
    float a2x = d6[3], a2y = d6[4], a2z = d6[5];

    float n1 = fmaxf(sqrtf(a1x*a1x + a1y*a1y + a1z*a1z), 1e-8f);
    float b1x = a1x / n1, b1y = a1y / n1, b1z = a1z / n1;

    float d = b1x*a2x + b1y*a2y + b1z*a2z;
    float px = a2x - d*b1x, py = a2y - d*b1y, pz = a2z - d*b1z;
    float n2 = fmaxf(sqrtf(px*px + py*py + pz*pz), 1e-8f);
    float b2x = px / n2, b2y = py / n2, b2z = pz / n2;

    float b3x = b1y*b2z - b1z*b2y;
    float b3y = b1z*b2x - b1x*b2z;
    float b3z = b1x*b2y - b1y*b2x;

    int iv = idx[c];
    const float* xc = X + ((size_t)b * Vv + iv) * 3;
    float cx = xc[0], cy = xc[1], cz = xc[2];
    const float* vn = Vn + (size_t)(b * Cv + c) * 3;
    float vx = vn[0], vy = vn[1], vz = vn[2];

    float* Ao = A + (size_t)(b * Cv + c) * 12;
    Ao[0] = b1x; Ao[1] = b1y; Ao[2] = b1z;
    Ao[3] = b2x; Ao[4] = b2y; Ao[5] = b2z;
    Ao[6] = b3x; Ao[7] = b3y; Ao[8] = b3z;
    Ao[9]  = cx + vx - (b1x*cx + b1y*cy + b1z*cz);
    Ao[10] = cy + vy - (b2x*cx + b2y*cy + b2z*cz);
    Ao[11] = cz + vz - (b3x*cx + b3y*cy + b3z*cz);
}

// Kernel 2: K-split x4. Grid = 782 vertex-tiles x 4 batches = 3128 blocks,
// 256 thr = 4 waves/block -> 12512 waves (48.9/CU, saturates residency).
// Wave w handles c in [40w, 40w+40) for this block's (tile, batch); lane =
// vertex. W: per-lane global float4 (vmcnt). A: base is blockIdx-derived ->
// provably scalar -> s_load on the scalar pipe (lgkmcnt), zero vector-issue
// cost. Short per-wave chain (10 c4-iters) x many waves = latency hidden by
// TLP. LDS only in the epilogue (4-way partial combine, stride-13 pad).
__global__ __launch_bounds__(256) void deform_main(const float* __restrict__ X,
                                                   const float* __restrict__ W,
                                                   const float* __restrict__ A,
                                                   float* __restrict__ out) {
    __shared__ float P[3 * 64 * 13];  // partials from waves 1..3

    const int tid  = threadIdx.x;
    const int lane = tid & 63;
    const int wv   = __builtin_amdgcn_readfirstlane(tid >> 6);  // 0..3 uniform
    const int b    = blockIdx.x & 3;          // scalar by construction
    const int tile = blockIdx.x >> 2;
    const int v0   = tile * 64;
    const int v    = v0 + lane;
    const bool valid = (v < Vv);
    const int vc   = valid ? v : (Vv - 1);

    // W: this wave's 10 float4s of the lane's row (vector path, vmcnt)
    const float4* __restrict__ Wrow =
        (const float4*)(W + (size_t)vc * Cv) + wv * 10;
    // A: scalar base + uniform offsets -> s_load
    const float* __restrict__ Ab = A + ((size_t)b * Cv + (size_t)wv * 40) * 12;

    float acc[12];
#pragma unroll
    for (int j = 0; j < 12; ++j) acc[j] = 0.0f;

#pragma unroll 2
    for (int c4 = 0; c4 < 10; ++c4) {
        float4 wq = Wrow[c4];
        const float wj[4] = {wq.x, wq.y, wq.z, wq.w};
#pragma unroll
        for (int j = 0; j < 4; ++j) {
            const float* a = Ab + (size_t)(c4 * 4 + j) * 12;  // uniform -> s_load
            float w = wj[j];
#pragma unroll
            for (int k = 0; k < 12; ++k) acc[k] = fmaf(w, a[k], acc[k]);
        }
    }

    // 4-way combine: waves 1..3 dump partials, wave 0 reduces + epilogue.
    if (wv) {
        float* p = &P[((wv - 1) * 64 + lane) * 13];
#pragma unroll
        for (int j = 0; j < 12; ++j) p[j] = acc[j];
    }
    __syncthreads();

    if (!wv && valid) {
#pragma unroll
        for (int h = 0; h < 3; ++h) {
            const float* p = &P[(h * 64 + lane) * 13];
#pragma unroll
            for (int j = 0; j < 12; ++j) acc[j] += p[j];
        }
        const float* xp = X + ((size_t)b * Vv + v) * 3;
        float x0 = xp[0], x1 = xp[1], x2 = xp[2];
        // acc[0..8] = M row-major, acc[9..11] = T
        float o0 = acc[0]*x0 + acc[1]*x1 + acc[2]*x2 + acc[9];
        float o1 = acc[3]*x0 + acc[4]*x1 + acc[5]*x2 + acc[10];
        float o2 = acc[6]*x0 + acc[7]*x1 + acc[8]*x2 + acc[11];
        float* op = out + ((size_t)b * Vv + v) * 3;
        op[0] = o0; op[1] = o1; op[2] = o2;
    }
}

extern "C" void kernel_launch(void* const* d_in, const int* in_sizes, int n_in,
                              void* d_out, int out_size, void* d_ws, size_t ws_size,
                              hipStream_t stream) {
    const float* X   = (const float*)d_in[0];  // (B,V,3) fp32
    const float* Vn  = (const float*)d_in[1];  // (B,C,3) fp32
    const float* r6  = (const float*)d_in[2];  // (B,C,6) fp32
    const float* W   = (const float*)d_in[3];  // (V,C)   fp32
    const int*   idx = (const int*)d_in[4];    // (C,)    int32
    float* out = (float*)d_out;                // (B,V,3) fp32
    float* A = (float*)d_ws;                   // B*C*12 floats = 30720 B

    precompute_A<<<(Bv * Cv + 255) / 256, 256, 0, stream>>>(X, Vn, r6, idx, A);
    deform_main<<<((Vv + 63) / 64) * Bv, 256, 0, stream>>>(X, W, A, out);
}

// Round 10
// 104.969 us; speedup vs baseline: 1.3244x; 1.1491x over previous
//
#include <hip/hip_runtime.h>

#define Bv 4
#define Vv 50000
#define Cv 160
#define TILES 782      // ceil(Vv/64)
#define TILES_PAD 784  // multiple of 8: siblings (same tile, diff b) share an XCD

// Kernel 1: per-(b,c) affine table A[b][c][12]:
//   A[0..8]  = R row-major (rows b1,b2,b3)
//   A[9..11] = center + V_nodes - R*center
// so out[b,v,:] = M·x_v + t with [M|t] = sum_c W[v,c]*A[b,c,:]
__global__ void precompute_A(const float* __restrict__ X,
                             const float* __restrict__ Vn,
                             const float* __restrict__ r6,
                             const int* __restrict__ idx,
                             float* __restrict__ A) {
    int i = blockIdx.x * blockDim.x + threadIdx.x;
    if (i >= Bv * Cv) return;
    int b = i / Cv, c = i % Cv;

    const float* d6 = r6 + (size_t)(b * Cv + c) * 6;
    float a1x = d6[0], a1y = d6[1], a1z = d6[2];
    float a2x = d6[3], a2y = d6[4], a2z = d6[5];

    float n1 = fmaxf(sqrtf(a1x*a1x + a1y*a1y + a1z*a1z), 1e-8f);
    float b1x = a1x / n1, b1y = a1y / n1, b1z = a1z / n1;

    float d = b1x*a2x + b1y*a2y + b1z*a2z;
    float px = a2x - d*b1x, py = a2y - d*b1y, pz = a2z - d*b1z;
    float n2 = fmaxf(sqrtf(px*px + py*py + pz*pz), 1e-8f);
    float b2x = px / n2, b2y = py / n2, b2z = pz / n2;

    float b3x = b1y*b2z - b1z*b2y;
    float b3y = b1z*b2x - b1x*b2z;
    float b3z = b1x*b2y - b1y*b2x;

    int iv = idx[c];
    const float* xc = X + ((size_t)b * Vv + iv) * 3;
    float cx = xc[0], cy = xc[1], cz = xc[2];
    const float* vn = Vn + (size_t)(b * Cv + c) * 3;
    float vx = vn[0], vy = vn[1], vz = vn[2];

    float* Ao = A + (size_t)(b * Cv + c) * 12;
    Ao[0] = b1x; Ao[1] = b1y; Ao[2] = b1z;
    Ao[3] = b2x; Ao[4] = b2y; Ao[5] = b2z;
    Ao[6] = b3x; Ao[7] = b3y; Ao[8] = b3z;
    Ao[9]  = cx + vx - (b1x*cx + b1y*cy + b1z*cz);
    Ao[10] = cy + vy - (b2x*cx + b2y*cy + b2z*cz);
    Ao[11] = cz + vz - (b3x*cx + b3y*cy + b3z*cz);
}

// Kernel 2: K-split x4, R9 structure, XCD-aligned grid mapping.
// blockIdx = b*TILES_PAD + tile  (TILES_PAD % 8 == 0), so the 4 sibling
// blocks of a tile map to XCD = tile % 8 — the SAME XCD. R9's consecutive
// (tile*4+b) mapping scattered siblings across 4 XCDs: each XCD L2 pulled
// its own copy of the W tile -> FETCH_SIZE 140 MB and remote-latency
// requests. Wave w of a block handles c in [40w, 40w+40); lane = vertex.
// W: per-lane global float4 (vmcnt). A: blockIdx-derived scalar base ->
// s_load (scalar pipe). LDS only in the 4-way combine epilogue.
__global__ __launch_bounds__(256) void deform_main(const float* __restrict__ X,
                                                   const float* __restrict__ W,
                                                   const float* __restrict__ A,
                                                   float* __restrict__ out) {
    __shared__ float P[3 * 64 * 13];  // partials from waves 1..3

    const int tile = blockIdx.x % TILES_PAD;
    const int b    = blockIdx.x / TILES_PAD;   // scalar by construction
    if (tile >= TILES) return;                  // 8 pad blocks, uniform exit

    const int tid  = threadIdx.x;
    const int lane = tid & 63;
    const int wv   = __builtin_amdgcn_readfirstlane(tid >> 6);  // 0..3 uniform
    const int v0   = tile * 64;
    const int v    = v0 + lane;
    const bool valid = (v < Vv);
    const int vc   = valid ? v : (Vv - 1);

    // W: this wave's 10 float4s of the lane's row (vector path, vmcnt)
    const float4* __restrict__ Wrow =
        (const float4*)(W + (size_t)vc * Cv) + wv * 10;
    // A: scalar base + uniform offsets -> s_load
    const float* __restrict__ Ab = A + ((size_t)b * Cv + (size_t)wv * 40) * 12;

    float acc[12];
#pragma unroll
    for (int j = 0; j < 12; ++j) acc[j] = 0.0f;

#pragma unroll 2
    for (int c4 = 0; c4 < 10; ++c4) {
        float4 wq = Wrow[c4];
        const float wj[4] = {wq.x, wq.y, wq.z, wq.w};
#pragma unroll
        for (int j = 0; j < 4; ++j) {
            const float* a = Ab + (size_t)(c4 * 4 + j) * 12;  // uniform -> s_load
            float w = wj[j];
#pragma unroll
            for (int k = 0; k < 12; ++k) acc[k] = fmaf(w, a[k], acc[k]);
        }
    }

    // 4-way combine: waves 1..3 dump partials, wave 0 reduces + epilogue.
    if (wv) {
        float* p = &P[((wv - 1) * 64 + lane) * 13];
#pragma unroll
        for (int j = 0; j < 12; ++j) p[j] = acc[j];
    }
    __syncthreads();

    if (!wv && valid) {
#pragma unroll
        for (int h = 0; h < 3; ++h) {
            const float* p = &P[(h * 64 + lane) * 13];
#pragma unroll
            for (int j = 0; j < 12; ++j) acc[j] += p[j];
        }
        const float* xp = X + ((size_t)b * Vv + v) * 3;
        float x0 = xp[0], x1 = xp[1], x2 = xp[2];
        // acc[0..8] = M row-major, acc[9..11] = T
        float o0 = acc[0]*x0 + acc[1]*x1 + acc[2]*x2 + acc[9];
        float o1 = acc[3]*x0 + acc[4]*x1 + acc[5]*x2 + acc[10];
        float o2 = acc[6]*x0 + acc[7]*x1 + acc[8]*x2 + acc[11];
        float* op = out + ((size_t)b * Vv + v) * 3;
        op[0] = o0; op[1] = o1; op[2] = o2;
    }
}

extern "C" void kernel_launch(void* const* d_in, const int* in_sizes, int n_in,
                              void* d_out, int out_size, void* d_ws, size_t ws_size,
                              hipStream_t stream) {
    const float* X   = (const float*)d_in[0];  // (B,V,3) fp32
    const float* Vn  = (const float*)d_in[1];  // (B,C,3) fp32
    const float* r6  = (const float*)d_in[2];  // (B,C,6) fp32
    const float* W   = (const float*)d_in[3];  // (V,C)   fp32
    const int*   idx = (const int*)d_in[4];    // (C,)    int32
    float* out = (float*)d_out;                // (B,V,3) fp32
    float* A = (float*)d_ws;                   // B*C*12 floats = 30720 B

    precompute_A<<<(Bv * Cv + 255) / 256, 256, 0, stream>>>(X, Vn, r6, idx, A);
    deform_main<<<TILES_PAD * Bv, 256, 0, stream>>>(X, W, A, out);
}